// Round 6
// baseline (396.507 us; speedup 1.0000x reference)
//
#include <hip/hip_runtime.h>

// SpeakerCrossAttention on MI355X (gfx950) — v6
//   prep  : per-batch chain + W1f->bf16 (tiny, unchanged)
//   alpha : persistent 256 blocks (1/CU), 8 sub-tiles of 64t, dbuf LDS,
//           ISSUE(j+2) -> GEMM(j) -> COMMIT(j+1) -> bar -> FINAL(j)
//           1 barrier/sub-tile; launch_bounds(512,1) so regs aren't capped at 128
//   blend : 4d x 4t units, 6 independent loads/iter, NT stores
// v5 failure: stage/compute never overlapped (HBM duty cycle 14%); blend was
// dependent-latency bound (unroll 1 + NT loads).

typedef __attribute__((ext_vector_type(8))) short short8;     // 8 bf16 = 16B
typedef __attribute__((ext_vector_type(4))) unsigned short ushort4v;
typedef __attribute__((ext_vector_type(4))) float f32x4;

#define T_DIM 8192
#define D_DIM 512

__device__ __forceinline__ unsigned short f2bf(float x) {  // RTNE f32 -> bf16
  unsigned u = __builtin_bit_cast(unsigned, x);
  u = (u + 0x7fffu + ((u >> 16) & 1u)) >> 16;
  return (unsigned short)u;
}

// ---------------- prep kernel (v1-verified) ----------------
__global__ __launch_bounds__(512) void prep_kernel(
    const float* __restrict__ spk_in, const float* __restrict__ Wsp,
    const float* __restrict__ bsp,    const float* __restrict__ Wv,
    const float* __restrict__ bv,     const float* __restrict__ Wo,
    const float* __restrict__ bo,     const float* __restrict__ gma,
    const float* __restrict__ bta,    const float* __restrict__ Wg1,
    const float* __restrict__ bg1,
    float* __restrict__ attnn, float* __restrict__ biasb,
    unsigned short* __restrict__ w1fx)
{
  int tid = threadIdx.x;
  int blk = blockIdx.x;

  if (blk >= 16) {                    // ---- W1f -> bf16 ----
    int base = (blk - 16) * 2048 + tid;
    #pragma unroll
    for (int i = 0; i < 4; ++i) {
      int idx = base + i * 512;
      int n = idx >> 9, k = idx & 511;
      w1fx[idx] = f2bf(Wg1[n * 1024 + k]);
    }
    return;
  }

  int b = blk;
  __shared__ __attribute__((aligned(16))) float s_spk[256];
  __shared__ __attribute__((aligned(16))) float s_x[512];
  __shared__ __attribute__((aligned(16))) float s_y[512];
  __shared__ float red[512];

  float se = (tid < 256) ? spk_in[b * 256 + tid] : 0.f;
  red[tid] = se * se;
  __syncthreads();
  for (int s = 256; s > 0; s >>= 1) {
    if (tid < s) red[tid] += red[tid + s];
    __syncthreads();
  }
  float scale = 1.f / fmaxf(sqrtf(red[0]), 1e-12f);
  if (tid < 256) s_spk[tid] = se * scale;
  __syncthreads();

  {
    const float* wr = Wsp + (size_t)tid * 256;
    f32x4 a4 = {0.f, 0.f, 0.f, 0.f};
    #pragma unroll 8
    for (int s2 = 0; s2 < 256; s2 += 4)
      a4 += (*(const f32x4*)(wr + s2)) * (*(const f32x4*)(s_spk + s2));
    s_x[tid] = a4[0] + a4[1] + a4[2] + a4[3] + bsp[tid];
  }
  __syncthreads();

  {
    const float* wr = Wv + (size_t)tid * 512;
    f32x4 a4 = {0.f, 0.f, 0.f, 0.f};
    #pragma unroll 8
    for (int s2 = 0; s2 < 512; s2 += 4)
      a4 += (*(const f32x4*)(wr + s2)) * (*(const f32x4*)(s_x + s2));
    s_y[tid] = a4[0] + a4[1] + a4[2] + a4[3] + bv[tid];
  }
  __syncthreads();

  float attnv;
  {
    const float* wr = Wo + (size_t)tid * 512;
    f32x4 a4 = {0.f, 0.f, 0.f, 0.f};
    #pragma unroll 8
    for (int s2 = 0; s2 < 512; s2 += 4)
      a4 += (*(const f32x4*)(wr + s2)) * (*(const f32x4*)(s_y + s2));
    attnv = a4[0] + a4[1] + a4[2] + a4[3] + bo[tid];
  }

  red[tid] = attnv;
  __syncthreads();
  for (int s = 256; s > 0; s >>= 1) {
    if (tid < s) red[tid] += red[tid + s];
    __syncthreads();
  }
  float mu = red[0] * (1.f / 512.f);
  __syncthreads();
  float dv = attnv - mu;
  red[tid] = dv * dv;
  __syncthreads();
  for (int s = 256; s > 0; s >>= 1) {
    if (tid < s) red[tid] += red[tid + s];
    __syncthreads();
  }
  float var = red[0] * (1.f / 512.f);
  float an = dv * rsqrtf(var + 1e-5f) * gma[tid] + bta[tid];
  s_x[tid] = an;
  attnn[b * 512 + tid] = an;
  __syncthreads();

  {
    const float* wr = Wg1 + (size_t)tid * 1024 + 512;
    f32x4 a4 = {0.f, 0.f, 0.f, 0.f};
    #pragma unroll 8
    for (int s2 = 0; s2 < 512; s2 += 4)
      a4 += (*(const f32x4*)(wr + s2)) * (*(const f32x4*)(s_x + s2));
    biasb[b * 512 + tid] = a4[0] + a4[1] + a4[2] + a4[3] + bg1[tid];
  }
}

// ---------------- alpha kernel: persistent, pipelined ----------------
// 256 blocks (1/CU). block: b = blk>>4, t-range = (blk&15)*512, 8 sub-tiles x 64t.
__global__ __launch_bounds__(512, 1) void alpha_kernel(
    const float* __restrict__ feat, const unsigned short* __restrict__ w1fx,
    const float* __restrict__ biasb, const float* __restrict__ wg2p,
    const float* __restrict__ bg2p,  float* __restrict__ alpha_out)
{
  __shared__ __attribute__((aligned(16))) unsigned short S[2][64 * 512]; // 128 KB
  __shared__ __attribute__((aligned(16))) float s_bias[512];
  __shared__ __attribute__((aligned(16))) float s_wg2[512];
  __shared__ float s_gpart[2][8 * 64];                                   // 4 KB

  int tid = threadIdx.x;
  int b      = blockIdx.x >> 4;
  int t0base = (blockIdx.x & 15) << 9;        // * 512
  const float* fbase = feat + (size_t)b * D_DIM * T_DIM + t0base;

  int mt = tid & 15, mk = tid >> 4;           // stage mapping
  int tt = mt * 4;

  f32x4 ra[16], rb[16];

#define ISSUE(J, RR) do {                                                   \
    const float* fb_ = fbase + (J) * 64 + tt;                               \
    _Pragma("unroll")                                                       \
    for (int it_ = 0; it_ < 2; ++it_) {                                     \
      int k0_ = mk * 8 + it_ * 256;                                         \
      _Pragma("unroll")                                                     \
      for (int q_ = 0; q_ < 8; ++q_)                                        \
        RR[it_ * 8 + q_] = *(const f32x4*)(fb_ + (size_t)(k0_ + q_) * T_DIM); \
    }                                                                       \
    __builtin_amdgcn_sched_barrier(0);                                      \
  } while (0)

#define COMMIT(RR, P) do {                                                  \
    char* Sb_ = (char*)S[P];                                                \
    _Pragma("unroll")                                                       \
    for (int it_ = 0; it_ < 2; ++it_) {                                     \
      int kbyte_ = (mk * 8 + it_ * 256) * 2;                                \
      _Pragma("unroll")                                                     \
      for (int i_ = 0; i_ < 4; ++i_) {                                      \
        short8 wv_;                                                         \
        _Pragma("unroll")                                                   \
        for (int q_ = 0; q_ < 8; ++q_)                                      \
          wv_[q_] = (short)f2bf(RR[it_ * 8 + q_][i_]);                      \
        int row_ = tt + i_;                                                 \
        int byte_ = (row_ << 10) + kbyte_;                                  \
        byte_ ^= (row_ & 7) << 4;                                           \
        *(short8*)(Sb_ + byte_) = wv_;                                      \
      }                                                                     \
    }                                                                       \
  } while (0)

  // GEMM lane mapping (v1-verified)
  int l = tid & 63, w = tid >> 6;
  int g = l >> 4, c = l & 15;
  int n0w = w * 64;
  const unsigned short* ap0 = w1fx + (size_t)(n0w + c) * 512 + g * 8;
  int xsw = (c & 7) << 4;
  int bb0 = (c << 10) + g * 16;

#define GEMMPART(P) do {                                                    \
    const char* Sb_ = (const char*)S[P];                                    \
    f32x4 acc[4][4];                                                        \
    _Pragma("unroll")                                                       \
    for (int i_ = 0; i_ < 4; ++i_)                                          \
      _Pragma("unroll")                                                     \
      for (int j_ = 0; j_ < 4; ++j_)                                        \
        acc[i_][j_] = (f32x4){0.f, 0.f, 0.f, 0.f};                          \
    _Pragma("unroll 2")                                                     \
    for (int kk = 0; kk < 16; ++kk) {                                       \
      short8 af[4], bf[4];                                                  \
      _Pragma("unroll")                                                     \
      for (int ni = 0; ni < 4; ++ni)                                        \
        af[ni] = *(const short8*)(ap0 + ni * (16 * 512) + kk * 32);         \
      _Pragma("unroll")                                                     \
      for (int tg = 0; tg < 4; ++tg)                                        \
        bf[tg] = *(const short8*)(Sb_ + ((bb0 + tg * 16384 + kk * 64) ^ xsw)); \
      _Pragma("unroll")                                                     \
      for (int ni = 0; ni < 4; ++ni)                                        \
        _Pragma("unroll")                                                   \
        for (int tg = 0; tg < 4; ++tg)                                      \
          acc[ni][tg] = __builtin_amdgcn_mfma_f32_16x16x32_bf16(            \
              af[ni], bf[tg], acc[ni][tg], 0, 0, 0);                        \
    }                                                                       \
    float p0 = 0.f, p1 = 0.f, p2 = 0.f, p3 = 0.f;                           \
    _Pragma("unroll")                                                       \
    for (int ni = 0; ni < 4; ++ni) {                                        \
      _Pragma("unroll")                                                     \
      for (int rr = 0; rr < 4; ++rr) {                                      \
        int n_ = n0w + 16 * ni + 4 * g + rr;                                \
        float bb_ = s_bias[n_], ww_ = s_wg2[n_];                            \
        p0 += fmaxf(acc[ni][0][rr] + bb_, 0.f) * ww_;                       \
        p1 += fmaxf(acc[ni][1][rr] + bb_, 0.f) * ww_;                       \
        p2 += fmaxf(acc[ni][2][rr] + bb_, 0.f) * ww_;                       \
        p3 += fmaxf(acc[ni][3][rr] + bb_, 0.f) * ww_;                       \
      }                                                                     \
    }                                                                       \
    p0 += __shfl_xor(p0, 16); p0 += __shfl_xor(p0, 32);                     \
    p1 += __shfl_xor(p1, 16); p1 += __shfl_xor(p1, 32);                     \
    p2 += __shfl_xor(p2, 16); p2 += __shfl_xor(p2, 32);                     \
    p3 += __shfl_xor(p3, 16); p3 += __shfl_xor(p3, 32);                     \
    if (l < 16) {                                                           \
      s_gpart[P][w * 64 +  0 + l] = p0;                                     \
      s_gpart[P][w * 64 + 16 + l] = p1;                                     \
      s_gpart[P][w * 64 + 32 + l] = p2;                                     \
      s_gpart[P][w * 64 + 48 + l] = p3;                                     \
    }                                                                       \
  } while (0)

  float bg2v = bg2p[0];

#define FINAL(P, J) do {                                                    \
    if (tid < 64) {                                                         \
      float gs_ = bg2v;                                                     \
      _Pragma("unroll")                                                     \
      for (int w2_ = 0; w2_ < 8; ++w2_) gs_ += s_gpart[P][w2_ * 64 + tid];  \
      alpha_out[(size_t)b * T_DIM + t0base + (J) * 64 + tid] =              \
          1.f / (1.f + expf(-gs_));                                         \
    }                                                                       \
  } while (0)

  // ---- prologue: tile 0 -> S0, tile 1 -> rb ----
  ISSUE(0, ra);
  s_bias[tid] = biasb[b * 512 + tid];
  s_wg2[tid]  = wg2p[tid];
  COMMIT(ra, 0);
  ISSUE(1, rb);
  __syncthreads();                    // S0 + bias visible

  // ---- 8 sub-tiles, 2 per iteration ----
  #pragma unroll 1
  for (int jj = 0; jj < 8; jj += 2) {
    if (jj + 2 < 8) ISSUE(jj + 2, ra);     // flies across GEMM+COMMIT
    GEMMPART(0);                            // tile jj from S0
    COMMIT(rb, 1);                          // tile jj+1 -> S1
    __syncthreads();
    FINAL(0, jj);

    if (jj + 3 < 8) ISSUE(jj + 3, rb);
    GEMMPART(1);                            // tile jj+1 from S1
    if (jj + 2 < 8) COMMIT(ra, 0);          // tile jj+2 -> S0
    __syncthreads();
    FINAL(1, jj + 1);
  }
#undef ISSUE
#undef COMMIT
#undef GEMMPART
#undef FINAL
}

// ---------------- blend kernel: 4d x 4t units, ILP ----------------
__global__ __launch_bounds__(256) void blend_kernel(
    const float* __restrict__ feat,  const float* __restrict__ alpha,
    const float* __restrict__ attnn, float* __restrict__ out)
{
  int u0 = blockIdx.x * 256 + threadIdx.x;
  const int NU = 16 * 128 * 2048;           // 4,194,304 units of 4d x 4t
  const int stride = 2048 * 256;
  #pragma unroll 2
  for (int u = u0; u < NU; u += stride) {
    int b  = u >> 18;
    int dq = (u >> 11) & 127;
    int t  = (u & 2047) << 2;
    int d0 = dq << 2;
    size_t fbase = ((size_t)(b * 512 + d0) << 13) + t;
    f32x4 a  = *(const f32x4*)(alpha + ((size_t)b << 13) + t);
    f32x4 an = *(const f32x4*)(attnn + b * 512 + d0);
    f32x4 f0 = *(const f32x4*)(feat + fbase);
    f32x4 f1 = *(const f32x4*)(feat + fbase + 8192);
    f32x4 f2 = *(const f32x4*)(feat + fbase + 16384);
    f32x4 f3 = *(const f32x4*)(feat + fbase + 24576);
    f32x4 o0, o1, o2, o3;
    #pragma unroll
    for (int j = 0; j < 4; ++j) {
      float om_a = 1.f - a[j];
      o0[j] = a[j] * f0[j] + om_a * an[0];
      o1[j] = a[j] * f1[j] + om_a * an[1];
      o2[j] = a[j] * f2[j] + om_a * an[2];
      o3[j] = a[j] * f3[j] + om_a * an[3];
    }
    __builtin_nontemporal_store(o0, (f32x4*)(out + fbase));
    __builtin_nontemporal_store(o1, (f32x4*)(out + fbase + 8192));
    __builtin_nontemporal_store(o2, (f32x4*)(out + fbase + 16384));
    __builtin_nontemporal_store(o3, (f32x4*)(out + fbase + 24576));
  }
}

extern "C" void kernel_launch(void* const* d_in, const int* in_sizes, int n_in,
                              void* d_out, int out_size, void* d_ws, size_t ws_size,
                              hipStream_t stream) {
  const float* features = (const float*)d_in[0];
  const float* spk      = (const float*)d_in[1];
  const float* Wsp      = (const float*)d_in[2];
  const float* bsp      = (const float*)d_in[3];
  const float* Wv       = (const float*)d_in[4];
  const float* bv       = (const float*)d_in[5];
  const float* Wo       = (const float*)d_in[6];
  const float* bo       = (const float*)d_in[7];
  const float* gma      = (const float*)d_in[8];
  const float* bta      = (const float*)d_in[9];
  const float* Wg1      = (const float*)d_in[10];
  const float* bg1      = (const float*)d_in[11];
  const float* Wg2      = (const float*)d_in[12];
  const float* bg2      = (const float*)d_in[13];
  float* out = (float*)d_out;

  // ws: attnn[8192] f32 | biasb[8192] f32 | alpha[131072] f32 | w1fx[262144] bf16
  float* attnn = (float*)d_ws;
  float* biasb = attnn + 8192;
  float* alpha = biasb + 8192;
  unsigned short* w1fx = (unsigned short*)(alpha + 131072);

  prep_kernel<<<144, 512, 0, stream>>>(spk, Wsp, bsp, Wv, bv, Wo, bo, gma, bta,
                                       Wg1, bg1, attnn, biasb, w1fx);
  alpha_kernel<<<256, 512, 0, stream>>>(features, w1fx, biasb, Wg2, bg2, alpha);
  blend_kernel<<<2048, 256, 0, stream>>>(features, alpha, attnn, out);
}

// Round 7
// 385.868 us; speedup vs baseline: 1.0276x; 1.0276x over previous
//
#include <hip/hip_runtime.h>

// SpeakerCrossAttention on MI355X (gfx950) — v7: fused, 4 blocks/CU, sane regs.
// B=16, D=512, T=8192, S=256. f32 in/out; GEMM in bf16 MFMA.
//
// Lessons baked in:
//  v1: fused 64t, 2 blocks/CU -> serial phases, 14% HBM duty (224us)
//  v2: 32t + (512,8) -> VGPR=32 strangled everything (330us)
//  v3/v4/v6: register-staged cross-tile prefetch -> compiler refuses >128 VGPR,
//            sinks/remats the prefetch (380/380/252us). Abandoned.
//  v5: split alpha/blend -> features read twice, still phase-serial (357us).
// v7: fused 32t tile, LDS 39.1KB -> 4 blocks/CU; all phases fit in <=~100 regs;
//     overlap comes statistically from 4 independent blocks per CU.
//     NT loads (features read once) + NT stores (out written once).
//     XOR bank swizzle on the bf16 tile.

typedef __attribute__((ext_vector_type(8))) short short8;     // 8 bf16 = 16B
typedef __attribute__((ext_vector_type(4))) unsigned short ushort4v;
typedef __attribute__((ext_vector_type(4))) float f32x4;

#define T_DIM 8192
#define D_DIM 512

__device__ __forceinline__ unsigned short f2bf(float x) {  // RTNE f32 -> bf16
  unsigned u = __builtin_bit_cast(unsigned, x);
  u = (u + 0x7fffu + ((u >> 16) & 1u)) >> 16;
  return (unsigned short)u;
}
__device__ __forceinline__ float bf2f(unsigned short h) {
  return __builtin_bit_cast(float, ((unsigned)h) << 16);
}

// ---------------- prep kernel (v1-verified) ----------------
__global__ __launch_bounds__(512) void prep_kernel(
    const float* __restrict__ spk_in, const float* __restrict__ Wsp,
    const float* __restrict__ bsp,    const float* __restrict__ Wv,
    const float* __restrict__ bv,     const float* __restrict__ Wo,
    const float* __restrict__ bo,     const float* __restrict__ gma,
    const float* __restrict__ bta,    const float* __restrict__ Wg1,
    const float* __restrict__ bg1,
    float* __restrict__ attnn, float* __restrict__ biasb,
    unsigned short* __restrict__ w1fx)
{
  int tid = threadIdx.x;
  int blk = blockIdx.x;

  if (blk >= 16) {                    // ---- W1f -> bf16 ----
    int base = (blk - 16) * 2048 + tid;
    #pragma unroll
    for (int i = 0; i < 4; ++i) {
      int idx = base + i * 512;
      int n = idx >> 9, k = idx & 511;
      w1fx[idx] = f2bf(Wg1[n * 1024 + k]);
    }
    return;
  }

  int b = blk;
  __shared__ __attribute__((aligned(16))) float s_spk[256];
  __shared__ __attribute__((aligned(16))) float s_x[512];
  __shared__ __attribute__((aligned(16))) float s_y[512];
  __shared__ float red[512];

  float se = (tid < 256) ? spk_in[b * 256 + tid] : 0.f;
  red[tid] = se * se;
  __syncthreads();
  for (int s = 256; s > 0; s >>= 1) {
    if (tid < s) red[tid] += red[tid + s];
    __syncthreads();
  }
  float scale = 1.f / fmaxf(sqrtf(red[0]), 1e-12f);
  if (tid < 256) s_spk[tid] = se * scale;
  __syncthreads();

  {
    const float* wr = Wsp + (size_t)tid * 256;
    f32x4 a4 = {0.f, 0.f, 0.f, 0.f};
    #pragma unroll 8
    for (int s2 = 0; s2 < 256; s2 += 4)
      a4 += (*(const f32x4*)(wr + s2)) * (*(const f32x4*)(s_spk + s2));
    s_x[tid] = a4[0] + a4[1] + a4[2] + a4[3] + bsp[tid];
  }
  __syncthreads();

  {
    const float* wr = Wv + (size_t)tid * 512;
    f32x4 a4 = {0.f, 0.f, 0.f, 0.f};
    #pragma unroll 8
    for (int s2 = 0; s2 < 512; s2 += 4)
      a4 += (*(const f32x4*)(wr + s2)) * (*(const f32x4*)(s_x + s2));
    s_y[tid] = a4[0] + a4[1] + a4[2] + a4[3] + bv[tid];
  }
  __syncthreads();

  float attnv;
  {
    const float* wr = Wo + (size_t)tid * 512;
    f32x4 a4 = {0.f, 0.f, 0.f, 0.f};
    #pragma unroll 8
    for (int s2 = 0; s2 < 512; s2 += 4)
      a4 += (*(const f32x4*)(wr + s2)) * (*(const f32x4*)(s_y + s2));
    attnv = a4[0] + a4[1] + a4[2] + a4[3] + bo[tid];
  }

  red[tid] = attnv;
  __syncthreads();
  for (int s = 256; s > 0; s >>= 1) {
    if (tid < s) red[tid] += red[tid + s];
    __syncthreads();
  }
  float mu = red[0] * (1.f / 512.f);
  __syncthreads();
  float dv = attnv - mu;
  red[tid] = dv * dv;
  __syncthreads();
  for (int s = 256; s > 0; s >>= 1) {
    if (tid < s) red[tid] += red[tid + s];
    __syncthreads();
  }
  float var = red[0] * (1.f / 512.f);
  float an = dv * rsqrtf(var + 1e-5f) * gma[tid] + bta[tid];
  s_x[tid] = an;
  attnn[b * 512 + tid] = an;
  __syncthreads();

  {
    const float* wr = Wg1 + (size_t)tid * 1024 + 512;
    f32x4 a4 = {0.f, 0.f, 0.f, 0.f};
    #pragma unroll 8
    for (int s2 = 0; s2 < 512; s2 += 4)
      a4 += (*(const f32x4*)(wr + s2)) * (*(const f32x4*)(s_x + s2));
    biasb[b * 512 + tid] = a4[0] + a4[1] + a4[2] + a4[3] + bg1[tid];
  }
}

// ---------------- fused main kernel: 32t tiles, 4 blocks/CU ----------------
__global__ __launch_bounds__(512, 1) void main_kernel(
    const float* __restrict__ feat, const unsigned short* __restrict__ w1fx,
    const float* __restrict__ attnn, const float* __restrict__ biasb,
    const float* __restrict__ wg2p,  const float* __restrict__ bg2p,
    float* __restrict__ out)
{
  __shared__ __attribute__((aligned(16))) unsigned short S[32 * 512]; // 32KB swz
  __shared__ __attribute__((aligned(16))) float s_attn[512];          // 2KB
  __shared__ __attribute__((aligned(16))) float s_bias[512];          // 2KB
  __shared__ __attribute__((aligned(16))) float s_wg2[512];           // 2KB
  __shared__ float s_gpart[8 * 32];                                   // 1KB
  __shared__ float s_alpha[32];                                       // 128B

  int tid = threadIdx.x;
  int b  = blockIdx.x >> 8;
  int t0 = (blockIdx.x & 255) << 5;
  const float* fb = feat + (size_t)b * D_DIM * T_DIM + t0;
  char* Sb = (char*)S;

  // ---- stage: 32t x 512k f32 -> bf16 LDS; 8 NT loads/thread, all in flight ----
  int mt = tid & 7, mk = tid >> 3;       // mt: t-chunk (4t), mk: 0..63 k-quads
  int tt = mt * 4;

  f32x4 r[8];
  #pragma unroll
  for (int it = 0; it < 2; ++it) {
    int k0 = (mk + it * 64) * 4;
    #pragma unroll
    for (int q = 0; q < 4; ++q)
      r[it * 4 + q] = __builtin_nontemporal_load(
          (const f32x4*)(fb + (size_t)(k0 + q) * T_DIM + tt));
  }
  s_attn[tid] = attnn[b * 512 + tid];
  s_bias[tid] = biasb[b * 512 + tid];
  s_wg2[tid]  = wg2p[tid];
  __builtin_amdgcn_sched_barrier(0);     // all 8 loads issued before commits

  #pragma unroll
  for (int it = 0; it < 2; ++it) {
    int kbyte = (mk + it * 64) * 8;      // 4 k * 2B
    #pragma unroll
    for (int i = 0; i < 4; ++i) {
      ushort4v wv;
      #pragma unroll
      for (int q = 0; q < 4; ++q)
        wv[q] = f2bf(r[it * 4 + q][i]);
      int row = tt + i;
      int byte = (row << 10) + kbyte;
      byte ^= (row & 7) << 4;            // bank swizzle
      *(ushort4v*)(Sb + byte) = wv;      // ds_write_b64
    }
  }
  __syncthreads();

  // ---- GEMM: h^T = W1f * F^T ; wave w: n in [64w,64w+64), t in [0,32) ----
  int l = tid & 63, w = tid >> 6;
  int g = l >> 4, c = l & 15;
  int n0w = w * 64;
  const unsigned short* ap0 = w1fx + (size_t)(n0w + c) * 512 + g * 8;
  int xsw = (c & 7) << 4;
  int bb0 = (c << 10) + g * 16;

  f32x4 acc[4][2];
  #pragma unroll
  for (int i = 0; i < 4; ++i)
    #pragma unroll
    for (int j = 0; j < 2; ++j)
      acc[i][j] = (f32x4){0.f, 0.f, 0.f, 0.f};

  #pragma unroll 2
  for (int kk = 0; kk < 16; ++kk) {
    short8 af[4], bf[2];
    #pragma unroll
    for (int ni = 0; ni < 4; ++ni)
      af[ni] = *(const short8*)(ap0 + ni * (16 * 512) + kk * 32);
    #pragma unroll
    for (int tg = 0; tg < 2; ++tg)
      bf[tg] = *(const short8*)(Sb + ((bb0 + tg * 16384 + kk * 64) ^ xsw));
    #pragma unroll
    for (int ni = 0; ni < 4; ++ni)
      #pragma unroll
      for (int tg = 0; tg < 2; ++tg)
        acc[ni][tg] = __builtin_amdgcn_mfma_f32_16x16x32_bf16(
            af[ni], bf[tg], acc[ni][tg], 0, 0, 0);
  }
  // lane l, reg rr of acc[ni][tg]: h[n = n0w+16ni+4g+rr][t = 16tg+c]

  // ---- alpha partials: g[t] = sum_n relu(h+bias)*wg2 ----
  float p0 = 0.f, p1 = 0.f;
  #pragma unroll
  for (int ni = 0; ni < 4; ++ni) {
    #pragma unroll
    for (int rr = 0; rr < 4; ++rr) {
      int n = n0w + 16 * ni + 4 * g + rr;
      float bb = s_bias[n], ww = s_wg2[n];
      p0 += fmaxf(acc[ni][0][rr] + bb, 0.f) * ww;
      p1 += fmaxf(acc[ni][1][rr] + bb, 0.f) * ww;
    }
  }
  p0 += __shfl_xor(p0, 16); p0 += __shfl_xor(p0, 32);
  p1 += __shfl_xor(p1, 16); p1 += __shfl_xor(p1, 32);
  if (l < 16) {
    s_gpart[w * 32 +  0 + l] = p0;
    s_gpart[w * 32 + 16 + l] = p1;
  }
  __syncthreads();
  if (tid < 32) {
    float gs = bg2p[0];
    #pragma unroll
    for (int w2 = 0; w2 < 8; ++w2) gs += s_gpart[w2 * 32 + tid];
    s_alpha[tid] = 1.f / (1.f + expf(-gs));
  }
  __syncthreads();

  // ---- blend + store: out[b,n,t0+t] = a*f + (1-a)*attn_n[n] ----
  {
    int tl = tid & 31, ng = tid >> 5;    // ng 0..15
    float al = s_alpha[tl], om = 1.f - al;
    float* ob = out + (size_t)b * D_DIM * T_DIM + t0 + tl;
    int rsw = (tl & 7) << 4;
    int rbase = tl << 10;
    #pragma unroll 4
    for (int it = 0; it < 8; ++it) {
      int n0 = it * 64 + ng * 4;
      ushort4v fv = *(const ushort4v*)(Sb + ((rbase + n0 * 2) ^ rsw));
      f32x4 an = *(const f32x4*)(&s_attn[n0]);
      #pragma unroll
      for (int i = 0; i < 4; ++i)
        __builtin_nontemporal_store(al * bf2f(fv[i]) + om * an[i],
                                    ob + (size_t)(n0 + i) * T_DIM);
    }
  }
}

extern "C" void kernel_launch(void* const* d_in, const int* in_sizes, int n_in,
                              void* d_out, int out_size, void* d_ws, size_t ws_size,
                              hipStream_t stream) {
  const float* features = (const float*)d_in[0];
  const float* spk      = (const float*)d_in[1];
  const float* Wsp      = (const float*)d_in[2];
  const float* bsp      = (const float*)d_in[3];
  const float* Wv       = (const float*)d_in[4];
  const float* bv       = (const float*)d_in[5];
  const float* Wo       = (const float*)d_in[6];
  const float* bo       = (const float*)d_in[7];
  const float* gma      = (const float*)d_in[8];
  const float* bta      = (const float*)d_in[9];
  const float* Wg1      = (const float*)d_in[10];
  const float* bg1      = (const float*)d_in[11];
  const float* Wg2      = (const float*)d_in[12];
  const float* bg2      = (const float*)d_in[13];
  float* out = (float*)d_out;

  // ws: attnn[8192] f32 | biasb[8192] f32 | w1fx[262144] bf16
  float* attnn = (float*)d_ws;
  float* biasb = attnn + 8192;
  unsigned short* w1fx = (unsigned short*)(biasb + 8192);

  prep_kernel<<<144, 512, 0, stream>>>(spk, Wsp, bsp, Wv, bv, Wo, bo, gma, bta,
                                       Wg1, bg1, attnn, biasb, w1fx);
  main_kernel<<<4096, 512, 0, stream>>>(features, w1fx, attnn, biasb, Wg2, bg2, out);
}

// Round 8
// 328.355 us; speedup vs baseline: 1.2076x; 1.1752x over previous
//
#include <hip/hip_runtime.h>

// SpeakerCrossAttention on MI355X (gfx950) — v8
// B=16, D=512, T=8192, S=256. f32 in/out; GEMM in bf16 MFMA.
//
// Diagnosis history: v1-v7 all latency/serialization-bound, never BW/compute.
// v8 root-cause fix: A(W1f) L2 gather was 16x64B scattered segments per load,
// 8192 line-requests per block, re-read per block (2 GB L2 traffic at 4096
// blocks). Now: (1) 128t tiles + 1024-thr blocks halve A traffic per t,
// (2) prep pre-permutes w1fx so af loads are contiguous 1KB per wave-instr,
// (3) K-chunk (BK=128) staging pipeline with raw s_barrier + lgkmcnt-only
//     (no vmcnt drain) so next chunk's HBM loads fly across barriers,
// (4) fused alpha+blend from the staged LDS tile (features read once).

typedef __attribute__((ext_vector_type(8))) short short8;     // 8 bf16 = 16B
typedef __attribute__((ext_vector_type(4))) unsigned short ushort4v;
typedef __attribute__((ext_vector_type(4))) float f32x4;

#define T_DIM 8192
#define D_DIM 512

__device__ __forceinline__ unsigned short f2bf(float x) {  // RTNE f32 -> bf16
  unsigned u = __builtin_bit_cast(unsigned, x);
  u = (u + 0x7fffu + ((u >> 16) & 1u)) >> 16;
  return (unsigned short)u;
}
__device__ __forceinline__ float bf2f(unsigned short h) {
  return __builtin_bit_cast(float, ((unsigned)h) << 16);
}

// ---------------- prep kernel ----------------
// blocks 0..15: per-batch chain (v1-verified). blocks 16..143: W1f -> bf16,
// PERMUTED layout: idx = ((((w*4 + c)*4 + kk)*2 + ni)*64 + l)*8 + e
//   maps to W1f[n][d], n = 32w + 16ni + (l&15), d = 128c + 32kk + 8*(l>>4) + e
// so the GEMM af load for (w,c,kk,ni) is 64 lanes x 16B CONTIGUOUS (1KB).
__global__ __launch_bounds__(512) void prep_kernel(
    const float* __restrict__ spk_in, const float* __restrict__ Wsp,
    const float* __restrict__ bsp,    const float* __restrict__ Wv,
    const float* __restrict__ bv,     const float* __restrict__ Wo,
    const float* __restrict__ bo,     const float* __restrict__ gma,
    const float* __restrict__ bta,    const float* __restrict__ Wg1,
    const float* __restrict__ bg1,
    float* __restrict__ attnn, float* __restrict__ biasb,
    unsigned short* __restrict__ w1fx)
{
  int tid = threadIdx.x;
  int blk = blockIdx.x;

  if (blk >= 16) {                    // ---- W1f -> bf16, permuted ----
    #pragma unroll
    for (int i = 0; i < 4; ++i) {
      int idx = (blk - 16) * 2048 + i * 512 + tid;
      int e  = idx & 7;
      int l  = (idx >> 3) & 63;
      int ni = (idx >> 9) & 1;
      int kk = (idx >> 10) & 3;
      int c  = (idx >> 12) & 3;
      int w  = (idx >> 14) & 15;
      int n = w * 32 + ni * 16 + (l & 15);
      int d = c * 128 + kk * 32 + (l >> 4) * 8 + e;
      w1fx[idx] = f2bf(Wg1[n * 1024 + d]);
    }
    return;
  }

  int b = blk;
  __shared__ __attribute__((aligned(16))) float s_spk[256];
  __shared__ __attribute__((aligned(16))) float s_x[512];
  __shared__ __attribute__((aligned(16))) float s_y[512];
  __shared__ float red[512];

  float se = (tid < 256) ? spk_in[b * 256 + tid] : 0.f;
  red[tid] = se * se;
  __syncthreads();
  for (int s = 256; s > 0; s >>= 1) {
    if (tid < s) red[tid] += red[tid + s];
    __syncthreads();
  }
  float scale = 1.f / fmaxf(sqrtf(red[0]), 1e-12f);
  if (tid < 256) s_spk[tid] = se * scale;
  __syncthreads();

  {
    const float* wr = Wsp + (size_t)tid * 256;
    f32x4 a4 = {0.f, 0.f, 0.f, 0.f};
    #pragma unroll 8
    for (int s2 = 0; s2 < 256; s2 += 4)
      a4 += (*(const f32x4*)(wr + s2)) * (*(const f32x4*)(s_spk + s2));
    s_x[tid] = a4[0] + a4[1] + a4[2] + a4[3] + bsp[tid];
  }
  __syncthreads();

  {
    const float* wr = Wv + (size_t)tid * 512;
    f32x4 a4 = {0.f, 0.f, 0.f, 0.f};
    #pragma unroll 8
    for (int s2 = 0; s2 < 512; s2 += 4)
      a4 += (*(const f32x4*)(wr + s2)) * (*(const f32x4*)(s_x + s2));
    s_y[tid] = a4[0] + a4[1] + a4[2] + a4[3] + bv[tid];
  }
  __syncthreads();

  float attnv;
  {
    const float* wr = Wo + (size_t)tid * 512;
    f32x4 a4 = {0.f, 0.f, 0.f, 0.f};
    #pragma unroll 8
    for (int s2 = 0; s2 < 512; s2 += 4)
      a4 += (*(const f32x4*)(wr + s2)) * (*(const f32x4*)(s_y + s2));
    attnv = a4[0] + a4[1] + a4[2] + a4[3] + bo[tid];
  }

  red[tid] = attnv;
  __syncthreads();
  for (int s = 256; s > 0; s >>= 1) {
    if (tid < s) red[tid] += red[tid + s];
    __syncthreads();
  }
  float mu = red[0] * (1.f / 512.f);
  __syncthreads();
  float dv = attnv - mu;
  red[tid] = dv * dv;
  __syncthreads();
  for (int s = 256; s > 0; s >>= 1) {
    if (tid < s) red[tid] += red[tid + s];
    __syncthreads();
  }
  float var = red[0] * (1.f / 512.f);
  float an = dv * rsqrtf(var + 1e-5f) * gma[tid] + bta[tid];
  s_x[tid] = an;
  attnn[b * 512 + tid] = an;
  __syncthreads();

  {
    const float* wr = Wg1 + (size_t)tid * 1024 + 512;
    f32x4 a4 = {0.f, 0.f, 0.f, 0.f};
    #pragma unroll 8
    for (int s2 = 0; s2 < 512; s2 += 4)
      a4 += (*(const f32x4*)(wr + s2)) * (*(const f32x4*)(s_x + s2));
    biasb[b * 512 + tid] = a4[0] + a4[1] + a4[2] + a4[3] + bg1[tid];
  }
}

// ---------------- main kernel ----------------
// 256 blocks (1/CU), 1024 thr (16 waves). block: b = blk>>4, t-seg (blk&15)*512,
// 4 tiles of 128t. Per tile: 4 K-chunks of 128d staged f32->bf16 into quarters
// of one 128KB LDS tile; GEMM consumes chunk i while chunk i+1's loads fly.
// Wave w computes n in [32w, 32w+32) for all 128 t. Then alpha + blend.
__global__ __launch_bounds__(1024) void main_kernel(
    const float* __restrict__ feat, const unsigned short* __restrict__ w1fx,
    const float* __restrict__ attnn, const float* __restrict__ biasb,
    const float* __restrict__ wg2p,  const float* __restrict__ bg2p,
    float* __restrict__ out)
{
  __shared__ __attribute__((aligned(16))) unsigned short S[128 * 512]; // 128KB swz
  __shared__ __attribute__((aligned(16))) float s_attn[512];
  __shared__ __attribute__((aligned(16))) float s_bias[512];
  __shared__ __attribute__((aligned(16))) float s_wg2[512];
  __shared__ float s_gpart[16 * 128];                                  // 8KB
  __shared__ float s_alpha[128];

  int tid = threadIdx.x;
  int b    = blockIdx.x >> 4;
  int tseg = blockIdx.x & 15;
  const float* fb = feat + (size_t)b * D_DIM * T_DIM + tseg * 512;
  char* Sb = (char*)S;

  // staging map: thread = (t-quad tt, d-quad dq)
  int tt = (tid & 31) * 4;
  int dq = tid >> 5;                 // 0..31

  f32x4 r[4];

  // barrier with LDS-wait only: global loads stay in flight across it
#define LBAR() do {                                                         \
    asm volatile("s_waitcnt lgkmcnt(0)" ::: "memory");                      \
    __builtin_amdgcn_s_barrier();                                           \
    __builtin_amdgcn_sched_barrier(0);                                      \
  } while (0)

#define ISSUE(J, CH) do {                                                   \
    const float* fp_ = fb + (size_t)((CH) * 128 + dq * 4) * T_DIM + (J) * 128 + tt; \
    r[0] = *(const f32x4*)(fp_);                                            \
    r[1] = *(const f32x4*)(fp_ + T_DIM);                                    \
    r[2] = *(const f32x4*)(fp_ + 2 * T_DIM);                                \
    r[3] = *(const f32x4*)(fp_ + 3 * T_DIM);                                \
    __builtin_amdgcn_sched_barrier(0);                                      \
  } while (0)

#define COMMIT(CH) do {                                                     \
    int db_ = (CH) * 256 + dq * 8;                                          \
    _Pragma("unroll")                                                       \
    for (int i_ = 0; i_ < 4; ++i_) {                                        \
      ushort4v wv_;                                                         \
      wv_[0] = f2bf(r[0][i_]); wv_[1] = f2bf(r[1][i_]);                     \
      wv_[2] = f2bf(r[2][i_]); wv_[3] = f2bf(r[3][i_]);                     \
      int row_ = tt + i_;                                                   \
      *(ushort4v*)(Sb + (row_ << 10) + (db_ ^ ((row_ & 7) << 4))) = wv_;    \
    }                                                                       \
  } while (0)

  // GEMM lane mapping (v1-verified fragment/acc layout)
  int l = tid & 63, w = tid >> 6;    // w 0..15: n-slice [32w, 32w+32)
  int cc = l & 15, g = l >> 4;
  const unsigned short* apw = w1fx + w * 16384;   // this wave's permuted A slice
  int xsw = (cc & 7) << 4;

  f32x4 acc[2][8];

#define GEMM_CHUNK(CH) do {                                                 \
    _Pragma("unroll")                                                       \
    for (int kk_ = 0; kk_ < 4; ++kk_) {                                     \
      short8 af0_ = *(const short8*)(apw + (((CH)*4 + kk_)*2 + 0)*512 + l*8); \
      short8 af1_ = *(const short8*)(apw + (((CH)*4 + kk_)*2 + 1)*512 + l*8); \
      _Pragma("unroll")                                                     \
      for (int tg_ = 0; tg_ < 8; ++tg_) {                                   \
        short8 bf_ = *(const short8*)(Sb + ((tg_*16 + cc) << 10) +          \
                        (((CH)*256 + kk_*64 + g*16) ^ xsw));                \
        acc[0][tg_] = __builtin_amdgcn_mfma_f32_16x16x32_bf16(              \
            af0_, bf_, acc[0][tg_], 0, 0, 0);                               \
        acc[1][tg_] = __builtin_amdgcn_mfma_f32_16x16x32_bf16(              \
            af1_, bf_, acc[1][tg_], 0, 0, 0);                               \
      }                                                                     \
    }                                                                       \
  } while (0)

  // ---- prologue ----
  ISSUE(0, 0);
  if (tid < 512) {
    s_attn[tid] = attnn[b * 512 + tid];
    s_bias[tid] = biasb[b * 512 + tid];
    s_wg2[tid]  = wg2p[tid];
  }
  float bg2v = bg2p[0];

  #pragma unroll 1
  for (int j = 0; j < 4; ++j) {
    #pragma unroll
    for (int ni = 0; ni < 2; ++ni)
      #pragma unroll
      for (int tg = 0; tg < 8; ++tg)
        acc[ni][tg] = (f32x4){0.f, 0.f, 0.f, 0.f};

    COMMIT(0); ISSUE(j, 1);              LBAR(); GEMM_CHUNK(0);
    COMMIT(1); ISSUE(j, 2);              LBAR(); GEMM_CHUNK(1);
    COMMIT(2); ISSUE(j, 3);              LBAR(); GEMM_CHUNK(2);
    COMMIT(3); if (j < 3) ISSUE(j+1, 0); LBAR(); GEMM_CHUNK(3);
    // acc[ni][tg] lane l reg rr: h[n = 32w+16ni+4g+rr][t = 16tg+cc]

    // ---- alpha: p[tg] = sum over this wave's 32 n of relu(h+bias)*wg2 ----
    float p[8];
    #pragma unroll
    for (int tg = 0; tg < 8; ++tg) p[tg] = 0.f;
    #pragma unroll
    for (int ni = 0; ni < 2; ++ni) {
      #pragma unroll
      for (int rr = 0; rr < 4; ++rr) {
        int n = w * 32 + ni * 16 + g * 4 + rr;
        float bb = s_bias[n], ww = s_wg2[n];
        #pragma unroll
        for (int tg = 0; tg < 8; ++tg)
          p[tg] += fmaxf(acc[ni][tg][rr] + bb, 0.f) * ww;
      }
    }
    #pragma unroll
    for (int tg = 0; tg < 8; ++tg) {
      p[tg] += __shfl_xor(p[tg], 16);
      p[tg] += __shfl_xor(p[tg], 32);
    }
    if (l < 16) {
      #pragma unroll
      for (int tg = 0; tg < 8; ++tg)
        s_gpart[w * 128 + tg * 16 + l] = p[tg];
    }
    LBAR();
    if (tid < 128) {
      float gs = bg2v;
      #pragma unroll
      for (int w2 = 0; w2 < 16; ++w2) gs += s_gpart[w2 * 128 + tid];
      s_alpha[tid] = 1.f / (1.f + expf(-gs));
    }
    LBAR();

    // ---- blend + store: out[b,d,t] = a*f + (1-a)*attn_n[d] ----
    {
      int tl = tid & 127, dg = tid >> 7;     // tl: t row, dg: 0..7
      float al = s_alpha[tl], om = 1.f - al;
      float* op = out + (size_t)b * D_DIM * T_DIM + tseg * 512 + j * 128 + tl;
      int rbase = tl << 10, rsw = (tl & 7) << 4;
      #pragma unroll
      for (int m = 0; m < 8; ++m) {
        int d0 = m * 64 + dg * 8;
        short8 fv = *(const short8*)(Sb + rbase + ((d0 * 2) ^ rsw));
        f32x4 an0 = *(const f32x4*)(&s_attn[d0]);
        f32x4 an1 = *(const f32x4*)(&s_attn[d0 + 4]);
        #pragma unroll
        for (int e = 0; e < 4; ++e) {
          __builtin_nontemporal_store(
              al * bf2f((unsigned short)fv[e]) + om * an0[e],
              op + (size_t)(d0 + e) * T_DIM);
          __builtin_nontemporal_store(
              al * bf2f((unsigned short)fv[e + 4]) + om * an1[e],
              op + (size_t)(d0 + e + 4) * T_DIM);
        }
      }
    }
    LBAR();   // protect S before next tile's COMMIT(0)
  }
#undef LBAR
#undef ISSUE
#undef COMMIT
#undef GEMM_CHUNK
}

extern "C" void kernel_launch(void* const* d_in, const int* in_sizes, int n_in,
                              void* d_out, int out_size, void* d_ws, size_t ws_size,
                              hipStream_t stream) {
  const float* features = (const float*)d_in[0];
  const float* spk      = (const float*)d_in[1];
  const float* Wsp      = (const float*)d_in[2];
  const float* bsp      = (const float*)d_in[3];
  const float* Wv       = (const float*)d_in[4];
  const float* bv       = (const float*)d_in[5];
  const float* Wo       = (const float*)d_in[6];
  const float* bo       = (const float*)d_in[7];
  const float* gma      = (const float*)d_in[8];
  const float* bta      = (const float*)d_in[9];
  const float* Wg1      = (const float*)d_in[10];
  const float* bg1      = (const float*)d_in[11];
  const float* Wg2      = (const float*)d_in[12];
  const float* bg2      = (const float*)d_in[13];
  float* out = (float*)d_out;

  // ws: attnn[8192] f32 | biasb[8192] f32 | w1fx[262144] bf16 (permuted)
  float* attnn = (float*)d_ws;
  float* biasb = attnn + 8192;
  unsigned short* w1fx = (unsigned short*)(biasb + 8192);

  prep_kernel<<<144, 512, 0, stream>>>(spk, Wsp, bsp, Wv, bv, Wo, bo, gma, bta,
                                       Wg1, bg1, attnn, biasb, w1fx);
  main_kernel<<<256, 1024, 0, stream>>>(features, w1fx, attnn, biasb, Wg2, bg2, out);
}

// Round 9
// 291.320 us; speedup vs baseline: 1.3611x; 1.1271x over previous
//
#include <hip/hip_runtime.h>

// SpeakerCrossAttention on MI355X (gfx950) — v9: DMA pipeline via global_load_lds.
// B=16, D=512, T=8192, S=256. f32 in/out; GEMM in bf16 MFMA.
//
//  prep    : per-batch chain -> attnn/biasb; W1f -> bf16 PERMUTED (v8-verified)
//  convert : features f32 [b,d,t] -> bf16 swizzled [t][k] tile images, stored
//            INSIDE d_out (tile (b,t0) lives in out rows d<256, cols t0..t0+31;
//            only the block owning that t-window reads it, then overwrites it)
//  main    : 256 persistent blocks x 1024 thr; 8 tiles of 64t; double-buffered
//            global_load_lds DMA; counted s_waitcnt vmcnt(32) at tile top (the
//            4 oldest = DMAs retire in order; blend stores never waited on);
//            GEMM (16 waves x 32n, contiguous permuted A) -> alpha -> blend.

typedef __attribute__((ext_vector_type(8))) short short8;     // 8 bf16 = 16B
typedef __attribute__((ext_vector_type(4))) unsigned short ushort4v;
typedef __attribute__((ext_vector_type(4))) float f32x4;
typedef __attribute__((ext_vector_type(4))) int int4v;

#define T_DIM 8192
#define D_DIM 512

__device__ __forceinline__ unsigned short f2bf(float x) {  // RTNE f32 -> bf16
  unsigned u = __builtin_bit_cast(unsigned, x);
  u = (u + 0x7fffu + ((u >> 16) & 1u)) >> 16;
  return (unsigned short)u;
}
__device__ __forceinline__ float bf2f(unsigned short h) {
  return __builtin_bit_cast(float, ((unsigned)h) << 16);
}

__device__ __forceinline__ void dma16(const void* g, void* l) {
  __builtin_amdgcn_global_load_lds(
      (const __attribute__((address_space(1))) void*)g,
      (__attribute__((address_space(3))) void*)l, 16, 0, 0);
}

// ---------------- prep kernel (v8-verified) ----------------
__global__ __launch_bounds__(512) void prep_kernel(
    const float* __restrict__ spk_in, const float* __restrict__ Wsp,
    const float* __restrict__ bsp,    const float* __restrict__ Wv,
    const float* __restrict__ bv,     const float* __restrict__ Wo,
    const float* __restrict__ bo,     const float* __restrict__ gma,
    const float* __restrict__ bta,    const float* __restrict__ Wg1,
    const float* __restrict__ bg1,
    float* __restrict__ attnn, float* __restrict__ biasb,
    unsigned short* __restrict__ w1fx)
{
  int tid = threadIdx.x;
  int blk = blockIdx.x;

  if (blk >= 16) {                    // ---- W1f -> bf16, permuted ----
    #pragma unroll
    for (int i = 0; i < 4; ++i) {
      int idx = (blk - 16) * 2048 + i * 512 + tid;
      int e  = idx & 7;
      int l  = (idx >> 3) & 63;
      int ni = (idx >> 9) & 1;
      int kk = (idx >> 10) & 3;
      int c  = (idx >> 12) & 3;
      int w  = (idx >> 14) & 15;
      int n = w * 32 + ni * 16 + (l & 15);
      int d = c * 128 + kk * 32 + (l >> 4) * 8 + e;
      w1fx[idx] = f2bf(Wg1[n * 1024 + d]);
    }
    return;
  }

  int b = blk;
  __shared__ __attribute__((aligned(16))) float s_spk[256];
  __shared__ __attribute__((aligned(16))) float s_x[512];
  __shared__ __attribute__((aligned(16))) float s_y[512];
  __shared__ float red[512];

  float se = (tid < 256) ? spk_in[b * 256 + tid] : 0.f;
  red[tid] = se * se;
  __syncthreads();
  for (int s = 256; s > 0; s >>= 1) {
    if (tid < s) red[tid] += red[tid + s];
    __syncthreads();
  }
  float scale = 1.f / fmaxf(sqrtf(red[0]), 1e-12f);
  if (tid < 256) s_spk[tid] = se * scale;
  __syncthreads();

  {
    const float* wr = Wsp + (size_t)tid * 256;
    f32x4 a4 = {0.f, 0.f, 0.f, 0.f};
    #pragma unroll 8
    for (int s2 = 0; s2 < 256; s2 += 4)
      a4 += (*(const f32x4*)(wr + s2)) * (*(const f32x4*)(s_spk + s2));
    s_x[tid] = a4[0] + a4[1] + a4[2] + a4[3] + bsp[tid];
  }
  __syncthreads();

  {
    const float* wr = Wv + (size_t)tid * 512;
    f32x4 a4 = {0.f, 0.f, 0.f, 0.f};
    #pragma unroll 8
    for (int s2 = 0; s2 < 512; s2 += 4)
      a4 += (*(const f32x4*)(wr + s2)) * (*(const f32x4*)(s_x + s2));
    s_y[tid] = a4[0] + a4[1] + a4[2] + a4[3] + bv[tid];
  }
  __syncthreads();

  float attnv;
  {
    const float* wr = Wo + (size_t)tid * 512;
    f32x4 a4 = {0.f, 0.f, 0.f, 0.f};
    #pragma unroll 8
    for (int s2 = 0; s2 < 512; s2 += 4)
      a4 += (*(const f32x4*)(wr + s2)) * (*(const f32x4*)(s_y + s2));
    attnv = a4[0] + a4[1] + a4[2] + a4[3] + bo[tid];
  }

  red[tid] = attnv;
  __syncthreads();
  for (int s = 256; s > 0; s >>= 1) {
    if (tid < s) red[tid] += red[tid + s];
    __syncthreads();
  }
  float mu = red[0] * (1.f / 512.f);
  __syncthreads();
  float dv = attnv - mu;
  red[tid] = dv * dv;
  __syncthreads();
  for (int s = 256; s > 0; s >>= 1) {
    if (tid < s) red[tid] += red[tid + s];
    __syncthreads();
  }
  float var = red[0] * (1.f / 512.f);
  float an = dv * rsqrtf(var + 1e-5f) * gma[tid] + bta[tid];
  s_x[tid] = an;
  attnn[b * 512 + tid] = an;
  __syncthreads();

  {
    const float* wr = Wg1 + (size_t)tid * 1024 + 512;
    f32x4 a4 = {0.f, 0.f, 0.f, 0.f};
    #pragma unroll 8
    for (int s2 = 0; s2 < 512; s2 += 4)
      a4 += (*(const f32x4*)(wr + s2)) * (*(const f32x4*)(s_x + s2));
    biasb[b * 512 + tid] = a4[0] + a4[1] + a4[2] + a4[3] + bg1[tid];
  }
}

// ---------------- convert kernel ----------------
// 4096 blocks (b = blk>>8, g32 = blk&255, t0 = g32*32), 512 thr, LDS 32KB.
// Builds the bf16 swizzled [32t][1024B] image of features tile (b, t0..t0+31)
// and stores it as a linear byte stream into out rows d<256 of the same t-window:
//   image byte x  ->  out byte ((b*512 + (x>>7))*8192 + t0)*4 + (x&127)
__global__ __launch_bounds__(512) void convert_kernel(
    const float* __restrict__ feat, float* out)
{
  __shared__ __attribute__((aligned(16))) unsigned short S[32 * 512]; // 32 KB
  int tid = threadIdx.x;
  int b = blockIdx.x >> 8, g32 = blockIdx.x & 255;
  int t0 = g32 * 32;
  const float* fb = feat + (size_t)b * D_DIM * T_DIM + t0;
  char* Sb = (char*)S;

  int mt = tid & 7, mk = tid >> 3;       // mt: t-quad, mk: 0..63 k-quads
  int tt = mt * 4;

  f32x4 r[8];
  #pragma unroll
  for (int it = 0; it < 2; ++it) {
    int k0 = (mk + it * 64) * 4;
    #pragma unroll
    for (int q = 0; q < 4; ++q)
      r[it * 4 + q] = __builtin_nontemporal_load(
          (const f32x4*)(fb + (size_t)(k0 + q) * T_DIM + tt));
  }
  __builtin_amdgcn_sched_barrier(0);

  #pragma unroll
  for (int it = 0; it < 2; ++it) {
    int kbyte = (mk + it * 64) * 8;
    #pragma unroll
    for (int i = 0; i < 4; ++i) {
      ushort4v wv;
      wv[0] = f2bf(r[it*4+0][i]); wv[1] = f2bf(r[it*4+1][i]);
      wv[2] = f2bf(r[it*4+2][i]); wv[3] = f2bf(r[it*4+3][i]);
      int row = tt + i;
      *(ushort4v*)(Sb + (row << 10) + (kbyte ^ ((row & 7) << 4))) = wv;
    }
  }
  __syncthreads();

  // copyout: 32KB linear LDS -> image (plain stores: keep image in L2/L3)
  char* ob = (char*)(out + (size_t)b * D_DIM * T_DIM + t0);
  #pragma unroll
  for (int q = 0; q < 4; ++q) {
    int x = q * 8192 + tid * 16;
    int4v v = *(const int4v*)(Sb + x);
    int dseg = x >> 7, off = x & 127;
    *(int4v*)(ob + (size_t)dseg * (T_DIM * 4) + off) = v;
  }
}

// ---------------- main kernel ----------------
// 256 blocks x 1024 thr (16 waves). b = blk>>4, tseg = blk&15 -> 8 tiles of 64t.
// Double-buffered DMA of 64KB tile images; counted vmcnt; GEMM+alpha+blend.
__global__ __launch_bounds__(1024) void main_kernel(
    float* out,                      // aliases the image source (see convert)
    const unsigned short* __restrict__ w1fx,
    const float* __restrict__ attnn, const float* __restrict__ biasb,
    const float* __restrict__ wg2p,  const float* __restrict__ bg2p)
{
  __shared__ __attribute__((aligned(16))) unsigned short S[2][32768]; // 2x64KB
  __shared__ __attribute__((aligned(16))) float s_attn[512];
  __shared__ __attribute__((aligned(16))) float s_bias[512];
  __shared__ __attribute__((aligned(16))) float s_wg2[512];
  __shared__ float s_gpart[16 * 64];
  __shared__ float s_alpha[64];

  int tid = threadIdx.x;
  int b = blockIdx.x >> 4, tseg = blockIdx.x & 15;
  int l = tid & 63, w = tid >> 6;
  char* outb = (char*)(out + (size_t)b * D_DIM * T_DIM);

  // per-lane DMA source offsets (tile-invariant part)
  size_t dmaoff[4];
  #pragma unroll
  for (int q = 0; q < 4; ++q) {
    int x = (w * 4 + q) * 1024 + l * 16;
    int sub = x >> 15, xx = x & 32767;
    int dseg = xx >> 7, off = xx & 127;
    dmaoff[q] = ((size_t)dseg * T_DIM + sub * 32) * 4 + off;
  }

#define DMA(T0, P) do {                                                     \
    char* lb_ = (char*)S + (P) * 65536 + (w * 4) * 1024;                    \
    const char* gb_ = outb + (size_t)(T0) * 4;                              \
    _Pragma("unroll")                                                       \
    for (int q_ = 0; q_ < 4; ++q_)                                          \
      dma16(gb_ + dmaoff[q_], lb_ + q_ * 1024);                             \
    __builtin_amdgcn_sched_barrier(0);                                      \
  } while (0)

  // ---- prologue ----
  DMA(tseg * 512, 0);
  if (tid < 512) {
    s_attn[tid] = attnn[b * 512 + tid];
    s_bias[tid] = biasb[b * 512 + tid];
    s_wg2[tid]  = wg2p[tid];
  }
  float bg2v = bg2p[0];

  int cc = l & 15, g = l >> 4;
  const unsigned short* apw = w1fx + w * 16384;
  int xsw = (cc & 7) << 4;

  #pragma unroll 1
  for (int j = 0; j < 8; ++j) {
    int P = j & 1;
    // tile top: drain the 4 oldest vm ops (= this tile's DMAs), not the stores
    __builtin_amdgcn_sched_barrier(0);
    if (j == 0) asm volatile("s_waitcnt vmcnt(0) lgkmcnt(0)" ::: "memory");
    else        asm volatile("s_waitcnt vmcnt(32) lgkmcnt(0)" ::: "memory");
    __builtin_amdgcn_s_barrier();
    __builtin_amdgcn_sched_barrier(0);

    if (j < 7) DMA(tseg * 512 + (j + 1) * 64, P ^ 1);

    // ---- GEMM: wave w -> n in [32w,32w+32), t in [0,64) ----
    const char* Sb = (const char*)S + P * 65536;
    f32x4 acc[2][4];
    #pragma unroll
    for (int i = 0; i < 2; ++i)
      #pragma unroll
      for (int t = 0; t < 4; ++t)
        acc[i][t] = (f32x4){0.f, 0.f, 0.f, 0.f};

    #pragma unroll 4
    for (int kk = 0; kk < 16; ++kk) {
      short8 af0 = *(const short8*)(apw + (kk * 2 + 0) * 512 + l * 8);
      short8 af1 = *(const short8*)(apw + (kk * 2 + 1) * 512 + l * 8);
      short8 bf[4];
      #pragma unroll
      for (int tg = 0; tg < 4; ++tg)
        bf[tg] = *(const short8*)(Sb + ((tg * 16 + cc) << 10) +
                                  ((kk * 64 + g * 16) ^ xsw));
      #pragma unroll
      for (int tg = 0; tg < 4; ++tg) {
        acc[0][tg] = __builtin_amdgcn_mfma_f32_16x16x32_bf16(af0, bf[tg], acc[0][tg], 0, 0, 0);
        acc[1][tg] = __builtin_amdgcn_mfma_f32_16x16x32_bf16(af1, bf[tg], acc[1][tg], 0, 0, 0);
      }
    }
    // acc[ni][tg] lane l reg rr: h[n = 32w+16ni+4g+rr][t = 16tg+cc]

    // ---- alpha ----
    float p[4] = {0.f, 0.f, 0.f, 0.f};
    #pragma unroll
    for (int ni = 0; ni < 2; ++ni) {
      #pragma unroll
      for (int rr = 0; rr < 4; ++rr) {
        int n = w * 32 + ni * 16 + g * 4 + rr;
        float bb = s_bias[n], ww = s_wg2[n];
        #pragma unroll
        for (int tg = 0; tg < 4; ++tg)
          p[tg] += fmaxf(acc[ni][tg][rr] + bb, 0.f) * ww;
      }
    }
    #pragma unroll
    for (int tg = 0; tg < 4; ++tg) {
      p[tg] += __shfl_xor(p[tg], 16);
      p[tg] += __shfl_xor(p[tg], 32);
    }
    if (l < 16) {
      #pragma unroll
      for (int tg = 0; tg < 4; ++tg)
        s_gpart[w * 64 + tg * 16 + l] = p[tg];
    }
    asm volatile("s_waitcnt lgkmcnt(0)" ::: "memory");
    __builtin_amdgcn_s_barrier();
    if (tid < 64) {
      float gs = bg2v;
      #pragma unroll
      for (int w2 = 0; w2 < 16; ++w2) gs += s_gpart[w2 * 64 + tid];
      s_alpha[tid] = 1.f / (1.f + expf(-gs));
    }
    asm volatile("s_waitcnt lgkmcnt(0)" ::: "memory");
    __builtin_amdgcn_s_barrier();

    // ---- blend: 32 NT store instrs per thread (vmcnt accounting!) ----
    {
      int tl = tid & 63, dg = tid >> 6;
      float al = s_alpha[tl], om = 1.f - al;
      float* op = out + (size_t)b * D_DIM * T_DIM + tseg * 512 + j * 64 + tl;
      int rb = tl << 10, rs = (tl & 7) << 4;
      #pragma unroll
      for (int m = 0; m < 4; ++m) {
        int d0 = m * 128 + dg * 8;
        short8 fv = *(const short8*)(Sb + rb + ((d0 * 2) ^ rs));
        f32x4 an0 = *(const f32x4*)(&s_attn[d0]);
        f32x4 an1 = *(const f32x4*)(&s_attn[d0 + 4]);
        #pragma unroll
        for (int e = 0; e < 4; ++e) {
          __builtin_nontemporal_store(
              al * bf2f((unsigned short)fv[e]) + om * an0[e],
              op + (size_t)(d0 + e) * T_DIM);
          __builtin_nontemporal_store(
              al * bf2f((unsigned short)fv[e + 4]) + om * an1[e],
              op + (size_t)(d0 + 4 + e) * T_DIM);
        }
      }
    }
  }
#undef DMA
}

extern "C" void kernel_launch(void* const* d_in, const int* in_sizes, int n_in,
                              void* d_out, int out_size, void* d_ws, size_t ws_size,
                              hipStream_t stream) {
  const float* features = (const float*)d_in[0];
  const float* spk      = (const float*)d_in[1];
  const float* Wsp      = (const float*)d_in[2];
  const float* bsp      = (const float*)d_in[3];
  const float* Wv       = (const float*)d_in[4];
  const float* bv       = (const float*)d_in[5];
  const float* Wo       = (const float*)d_in[6];
  const float* bo       = (const float*)d_in[7];
  const float* gma      = (const float*)d_in[8];
  const float* bta      = (const float*)d_in[9];
  const float* Wg1      = (const float*)d_in[10];
  const float* bg1      = (const float*)d_in[11];
  const float* Wg2      = (const float*)d_in[12];
  const float* bg2      = (const float*)d_in[13];
  float* out = (float*)d_out;

  // ws: attnn[8192] f32 | biasb[8192] f32 | w1fx[262144] bf16 (permuted)
  float* attnn = (float*)d_ws;
  float* biasb = attnn + 8192;
  unsigned short* w1fx = (unsigned short*)(biasb + 8192);

  prep_kernel<<<144, 512, 0, stream>>>(spk, Wsp, bsp, Wv, bv, Wo, bo, gma, bta,
                                       Wg1, bg1, attnn, biasb, w1fx);
  convert_kernel<<<4096, 512, 0, stream>>>(features, out);
  main_kernel<<<256, 1024, 0, stream>>>(out, w1fx, attnn, biasb, Wg2, bg2);
}